// Round 1
// baseline (4869.918 us; speedup 1.0000x reference)
//
#include <hip/hip_runtime.h>
#include <hip/hip_bf16.h>
#include <stdint.h>

// ---------------------------------------------------------------------------
// VGG attention-erase pipeline, bf16 MFMA implicit-im2col convs.
// Activations are channels-last, spatially padded: [b][30 rows][32 cols][C] bf16.
// Weights pre-transposed to [p=9][O][C] bf16 so MFMA B-frags are 16B row reads.
// Conv GEMM: wave = 112 spatial (A, from LDS) x 64 outch (B, global->VGPR),
// block = 2 batches x 112 spatial x 128 outch, K-chunk = 32 channels,
// 9 shift positions reuse the same LDS patch (6x32 rows/cols per batch half).
// LDS patch staged with global_load_lds(16B) using an XOR swizzle on the
// 16B-unit index so ds_read_b128 fragment reads are <=2-way bank conflicted.
// ---------------------------------------------------------------------------

typedef __attribute__((ext_vector_type(8))) short short8;
typedef __attribute__((ext_vector_type(4))) float floatx4;

__device__ __forceinline__ unsigned short f2bf(float f) {
  union { float f; uint32_t u; } cv; cv.f = f;
  uint32_t u = cv.u;
  u += 0x7fffu + ((u >> 16) & 1u);   // round-to-nearest-even
  return (unsigned short)(u >> 16);
}

// ---------------- weight prep: w[O][C][3][3] f32 -> wt[9][O][C] bf16 --------
__global__ void wprep3(const float* __restrict__ w, unsigned short* __restrict__ wt,
                       int O, int C) {
  int i = blockIdx.x * 256 + threadIdx.x;
  int total = 9 * O * C;
  if (i >= total) return;
  int p = i / (O * C);
  int r = i - p * O * C;
  int o = r / C;
  int c = r - o * C;
  wt[i] = f2bf(w[(size_t)(o * C + c) * 9 + p]);
}

// -------------- weight prep 1x1: w[O][C] f32 -> wt[OP][C] bf16 (zero pad) ---
__global__ void wprep1(const float* __restrict__ w, unsigned short* __restrict__ wt,
                       int O, int OP, int C) {
  int i = blockIdx.x * 256 + threadIdx.x;
  if (i >= OP * C) return;
  int o = i / C, c = i - o * C;
  wt[i] = (o < O) ? f2bf(w[(size_t)o * C + c]) : (unsigned short)0;
}

// ------ avgpool 3x3/9 (count_include_pad) + transpose to ch-last padded -----
// x: [32][512][28][28] f32  ->  fp: [32][30][32][512] bf16 (borders zero)
__global__ void avgpool_k(const float* __restrict__ x, unsigned short* __restrict__ fp) {
  const int C = 512;
  int b = blockIdx.x, r = blockIdx.y, cg = blockIdx.z;  // r: padded row 0..29
  int t = threadIdx.x;
  __shared__ float xs[3 * 128 * 29];   // stride 29 to kill bank conflicts
  if (r == 0 || r == 29) {
    for (int i = t; i < 32 * 128; i += 256) {
      int c = i & 127, col = i >> 7;
      fp[((size_t)(b * 30 + r) * 32 + col) * C + cg * 128 + c] = 0;
    }
    return;
  }
  // stage feat rows fy = r-2 .. r (clipped; OOB rows -> 0)
  for (int i = t; i < 3 * 128 * 28; i += 256) {
    int dy = i / 3584;
    int rem = i - dy * 3584;
    int c = rem / 28, fx = rem - c * 28;
    int fy = r - 2 + dy;
    float v = (fy >= 0 && fy < 28)
                  ? x[((size_t)(b * 512 + cg * 128 + c) * 28 + fy) * 28 + fx]
                  : 0.f;
    xs[(dy * 128 + c) * 29 + fx] = v;
  }
  __syncthreads();
  for (int i = t; i < 32 * 128; i += 256) {
    int c = i & 127, col = i >> 7;
    float v = 0.f;
    if (col >= 1 && col <= 28) {
      int fx0 = col - 1;
#pragma unroll
      for (int dy = 0; dy < 3; ++dy)
#pragma unroll
        for (int dx = 0; dx < 3; ++dx) {
          int fx = fx0 - 1 + dx;
          if (fx >= 0 && fx < 28) v += xs[(dy * 128 + c) * 29 + fx];
        }
      v *= (1.f / 9.f);
    }
    fp[((size_t)(b * 30 + r) * 32 + col) * C + cg * 128 + c] = f2bf(v);
  }
}

// ---------- zero the padded borders of h1p/h2p (ws is poisoned per call) ----
__global__ void zero_borders(unsigned short* __restrict__ h1,
                             unsigned short* __restrict__ h2, int Mch) {
  int i = blockIdx.x * 256 + threadIdx.x;
  int vch = Mch >> 3;                      // uint4 = 8 bf16
  int perbuf = 32 * 176 * vch;
  if (i >= 2 * perbuf) return;
  unsigned short* h = (i < perbuf) ? h1 : h2;
  int j = (i < perbuf) ? i : i - perbuf;
  int cv = j % vch;
  int rr = j / vch;
  int bidx = rr / 176, e = rr - bidx * 176;
  int row, col;
  if (e < 32)      { row = 0;  col = e; }
  else if (e < 64) { row = 29; col = e - 32; }
  else {
    int q = e - 64;
    row = 1 + (q >> 2);
    int k = q & 3;
    col = (k == 0) ? 0 : 28 + k;           // cols 0,29,30,31
  }
  size_t addr = ((size_t)(bidx * 30 + row) * 32 + col) * Mch + cv * 8;
  *(uint4*)&h[addr] = (uint4){0u, 0u, 0u, 0u};
}

// ------------------------------- the conv GEMM ------------------------------
// fin: [B][30][32][C] bf16, wt: [P][M][C] bf16, bias: [OB] f32
// PADOUT=1: out bf16 [B][30][32][M] (interior only). PADOUT=0: out f32 [B][784][M].
template <int P, int RELU, int PADOUT>
__global__ __launch_bounds__(256, 2)
void conv_mfma(const unsigned short* __restrict__ fin,
               const unsigned short* __restrict__ wt,
               const float* __restrict__ bias,
               void* __restrict__ outp, int C, int M, int OB) {
  const int tid = threadIdx.x;
  const int lane = tid & 63;
  const int wave = tid >> 6;
  const int hB = wave & 1;      // batch half
  const int wo = wave >> 1;     // outch half
  const int ln = lane & 15;
  const int kq = lane >> 4;

  const int o0 = blockIdx.x * 128 + wo * 64;
  const int yo0 = blockIdx.y * 4;           // first output row of tile
  const int b0 = blockIdx.z * 2;
  const int bb = b0 + hB;

  __shared__ unsigned short ldsB[2 * 768 * 8];   // 24576 B: 2 halves x 768 units x 16B

  // spatial decomposition for A-fragment reads (m = ln within each 16-tile)
  int baserc[7];
#pragma unroll
  for (int mi = 0; mi < 7; ++mi) {
    int n = mi * 16 + ln;
    int y = n / 28, x = n - y * 28;
    baserc[mi] = y * 32 + x;
  }

  floatx4 acc[7][4];
#pragma unroll
  for (int mi = 0; mi < 7; ++mi)
#pragma unroll
    for (int ni = 0; ni < 4; ++ni)
      acc[mi][ni] = (floatx4){0.f, 0.f, 0.f, 0.f};

  const size_t fin_base0 = (size_t)(b0 * 30 + yo0) * 32 * C;
  const size_t fin_base1 = (size_t)((b0 + 1) * 30 + yo0) * 32 * C;

  for (int ck = 0; ck < C; ck += 32) {
    __syncthreads();
    // stage 2 x 768 16B-units: unit u holds (rc=u>>2, cg=(u&3)^(rc&3)) -> swizzle
#pragma unroll
    for (int it = 0; it < 6; ++it) {
      int wb = (it >= 3) ? 1 : 0;
      int u = (it - wb * 3) * 256 + tid;
      int rc = u >> 2;
      int cg = (u & 3) ^ (rc & 3);
      size_t goff = (wb ? fin_base1 : fin_base0) + (size_t)rc * C + ck + cg * 8;
      unsigned short* lp = &ldsB[(size_t)(wb * 768 + (it - wb * 3) * 256 + wave * 64) * 8];
      __builtin_amdgcn_global_load_lds((const uint32_t*)(fin + goff), (uint32_t*)lp,
                                       16, 0, 0);
    }
    __syncthreads();

#pragma unroll
    for (int p = 0; p < P; ++p) {
      int dy, dx;
      if (P == 1) { dy = 1; dx = 1; } else { dy = p / 3; dx = p - dy * 3; }
      // weight B-frags: global -> VGPR (16B contiguous rows of wt[p])
      short8 wf[4];
#pragma unroll
      for (int ni = 0; ni < 4; ++ni) {
        int o = o0 + ni * 16 + ln;
        wf[ni] = *(const short8*)(const void*)(wt + (size_t)(p * M + o) * C + ck + kq * 8);
      }
      // activation A-frags: LDS (swizzled)
      short8 af[7];
#pragma unroll
      for (int mi = 0; mi < 7; ++mi) {
        int rc = baserc[mi] + dy * 32 + dx;
        int u = hB * 768 + (rc << 2) + (kq ^ (rc & 3));
        af[mi] = *(const short8*)(const void*)&ldsB[(unsigned)u * 8];
      }
#pragma unroll
      for (int mi = 0; mi < 7; ++mi)
#pragma unroll
        for (int ni = 0; ni < 4; ++ni)
          acc[mi][ni] = __builtin_amdgcn_mfma_f32_16x16x32_bf16(af[mi], wf[ni],
                                                                acc[mi][ni], 0, 0, 0);
    }
  }

  // epilogue: D[row=spatial=(kq*4+j within 16-tile)][col=outch=ln]
  float bia[4];
#pragma unroll
  for (int ni = 0; ni < 4; ++ni) {
    int o = o0 + ni * 16 + ln;
    bia[ni] = (o < OB) ? bias[o] : 0.f;
  }
#pragma unroll
  for (int mi = 0; mi < 7; ++mi) {
#pragma unroll
    for (int j = 0; j < 4; ++j) {
      int n = mi * 16 + kq * 4 + j;
      int y = n / 28, x = n - y * 28;
#pragma unroll
      for (int ni = 0; ni < 4; ++ni) {
        int o = o0 + ni * 16 + ln;
        float v = acc[mi][ni][j] + bia[ni];
        if (RELU) v = fmaxf(v, 0.f);
        if (PADOUT) {
          size_t addr = ((size_t)(bb * 30 + yo0 + y + 1) * 32 + (x + 1)) * M + o;
          ((unsigned short*)outp)[addr] = f2bf(v);
        } else {
          size_t addr = ((size_t)bb * 784 + (yo0 + y) * 28 + x) * M + o;
          ((float*)outp)[addr] = v;
        }
      }
    }
  }
}

// ------------- logits (+ optional attention/mask), one block per batch ------
// ob: [32][784][256] f32 (cols 200..255 are zero)
template <int DO_ATTEN>
__global__ void logits_atten(const float* __restrict__ ob, const int* __restrict__ label,
                             float* __restrict__ outp, float* __restrict__ mask) {
  int b = blockIdx.x, t = threadIdx.x;
  const float* base = ob + (size_t)b * 784 * 256;
  float s = 0.f;
#pragma unroll 16
  for (int n = 0; n < 784; ++n) s += base[(size_t)n * 256 + t];
  if (t < 200) outp[b * 200 + t] = 1.f / (1.f + expf(-s * (1.f / 784.f)));

  if (DO_ATTEN) {
    __shared__ float labf[256];
    __shared__ float red[16];
    labf[t] = (t < 200) ? (float)label[b * 200 + t] : 0.f;
    __syncthreads();
    // normalization is invariant to the /cnt scaling -> skip it
    float att[4];
    float mn = 1e30f, mx = -1e30f;
#pragma unroll
    for (int i = 0; i < 4; ++i) {
      int n = t + i * 256;
      float a = 0.f;
      if (n < 784) {
        const float* rowp = base + (size_t)n * 256;
#pragma unroll 8
        for (int c = 0; c < 200; ++c) a += labf[c] * rowp[c];
        mn = fminf(mn, a);
        mx = fmaxf(mx, a);
      }
      att[i] = a;
    }
    for (int off = 32; off; off >>= 1) {
      mn = fminf(mn, __shfl_down(mn, off, 64));
      mx = fmaxf(mx, __shfl_down(mx, off, 64));
    }
    if ((t & 63) == 0) { red[(t >> 6) * 2] = mn; red[(t >> 6) * 2 + 1] = mx; }
    __syncthreads();
    if (t == 0) {
      float a = red[0], c = red[1];
      for (int wv = 1; wv < 4; ++wv) {
        a = fminf(a, red[wv * 2]);
        c = fmaxf(c, red[wv * 2 + 1]);
      }
      red[0] = a; red[1] = c;
    }
    __syncthreads();
    float gmn = red[0];
    float inv = 1.f / (red[1] - gmn);
#pragma unroll
    for (int i = 0; i < 4; ++i) {
      int n = t + i * 256;
      if (n < 784)
        mask[b * 784 + n] = ((att[i] - gmn) * inv >= 0.6f) ? 0.f : 1.f;
    }
  }
}

// ------------------- erase: featp interior *= mask (in place) ---------------
__global__ void erase_k(unsigned short* __restrict__ fp, const float* __restrict__ mask) {
  int i = blockIdx.x * 256 + threadIdx.x;
  if (i >= 32 * 28 * 28 * 512) return;
  int c = i & 511;
  int r2 = i >> 9;
  int xcol = r2 % 28;
  int r3 = r2 / 28;
  int y = r3 % 28;
  int b = r3 / 28;
  if (mask[b * 784 + y * 28 + xcol] == 0.f)
    fp[((size_t)(b * 30 + y + 1) * 32 + (xcol + 1)) * 512 + c] = 0;
}

// ---------------------------------------------------------------------------
extern "C" void kernel_launch(void* const* d_in, const int* in_sizes, int n_in,
                              void* d_out, int out_size, void* d_ws, size_t ws_size,
                              hipStream_t stream) {
  const float* x   = (const float*)d_in[0];
  const int* label = (const int*)d_in[1];
  const float* w1  = (const float*)d_in[2];
  const float* b1  = (const float*)d_in[3];
  const float* w2  = (const float*)d_in[4];
  const float* b2  = (const float*)d_in[5];
  const float* w3  = (const float*)d_in[6];
  const float* b3  = (const float*)d_in[7];
  const float* we1 = (const float*)d_in[8];
  const float* be1 = (const float*)d_in[9];
  const float* we2 = (const float*)d_in[10];
  const float* be2 = (const float*)d_in[11];
  const float* we3 = (const float*)d_in[12];
  const float* be3 = (const float*)d_in[13];
  float* outv = (float*)d_out;

  char* wp = (char*)d_ws;
  unsigned short* featp = (unsigned short*)wp; wp += 31457280;   // [32][30][32][512] bf16
  unsigned short* h1p   = (unsigned short*)wp; wp += 62914560;   // [32][30][32][1024] bf16
  unsigned short* h2p   = (unsigned short*)wp; wp += 62914560;
  unsigned short* Wt1   = (unsigned short*)wp; wp += 9437184;    // [9][1024][512]
  unsigned short* Wt2   = (unsigned short*)wp; wp += 18874368;   // [9][1024][1024]
  unsigned short* Wt3   = (unsigned short*)wp; wp += 524288;     // [256][1024]
  float* outbuf         = (float*)wp;          wp += 25690112;   // [32][784][256] f32
  float* maskb          = (float*)wp;          wp += 100352;     // [32][784]

  // prep (every launch: ws is re-poisoned by the harness)
  zero_borders<<<5632, 256, 0, stream>>>(h1p, h2p, 1024);
  avgpool_k<<<dim3(32, 30, 4), 256, 0, stream>>>(x, featp);
  wprep3<<<(9 * 1024 * 512 + 255) / 256, 256, 0, stream>>>(w1, Wt1, 1024, 512);
  wprep3<<<(9 * 1024 * 1024 + 255) / 256, 256, 0, stream>>>(w2, Wt2, 1024, 1024);
  wprep1<<<(256 * 1024 + 255) / 256, 256, 0, stream>>>(w3, Wt3, 200, 256, 1024);

  // head 1
  conv_mfma<9, 1, 1><<<dim3(8, 7, 16), 256, 0, stream>>>(featp, Wt1, b1, h1p, 512, 1024, 1024);
  conv_mfma<9, 1, 1><<<dim3(8, 7, 16), 256, 0, stream>>>(h1p, Wt2, b2, h2p, 1024, 1024, 1024);
  conv_mfma<1, 0, 0><<<dim3(2, 7, 16), 256, 0, stream>>>(h2p, Wt3, b3, outbuf, 1024, 256, 200);
  logits_atten<1><<<32, 256, 0, stream>>>(outbuf, label, outv, maskb);

  // erase + head 2 (reuse Wt/h buffers; h borders are still zero)
  erase_k<<<(32 * 28 * 28 * 512 + 255) / 256, 256, 0, stream>>>(featp, maskb);
  wprep3<<<(9 * 1024 * 512 + 255) / 256, 256, 0, stream>>>(we1, Wt1, 1024, 512);
  wprep3<<<(9 * 1024 * 1024 + 255) / 256, 256, 0, stream>>>(we2, Wt2, 1024, 1024);
  wprep1<<<(256 * 1024 + 255) / 256, 256, 0, stream>>>(we3, Wt3, 200, 256, 1024);
  conv_mfma<9, 1, 1><<<dim3(8, 7, 16), 256, 0, stream>>>(featp, Wt1, be1, h1p, 512, 1024, 1024);
  conv_mfma<9, 1, 1><<<dim3(8, 7, 16), 256, 0, stream>>>(h1p, Wt2, be2, h2p, 1024, 1024, 1024);
  conv_mfma<1, 0, 0><<<dim3(2, 7, 16), 256, 0, stream>>>(h2p, Wt3, be3, outbuf, 1024, 256, 200);
  logits_atten<0><<<32, 256, 0, stream>>>(outbuf, nullptr, outv + 6400, nullptr);
}